// Round 1
// baseline (243.988 us; speedup 1.0000x reference)
//
#include <hip/hip_runtime.h>
#include <math.h>

// Problem constants (fixed by the reference file)
#define NN 100000
#define EE 1600000
#define DIM 128

// Partition parameters
#define BK 512                 // nodes per coarse bucket (dst >> 9)
#define NBK2 196               // ceil(NN / 512)
#define NCH 256                // edge-chunk blocks
#define EPB 6250               // EE / NCH
#define SCN (NBK2 * NCH)       // 50176 = 49 * 1024 exactly
#define NSB 49                 // scan blocks

typedef _Float16 half8 __attribute__((ext_vector_type(8)));
typedef _Float16 half2v __attribute__((ext_vector_type(2)));
typedef float f32x4 __attribute__((ext_vector_type(4)));

// ---------------------------------------------------------------------------
// Kernel 0: Bt[n*128+k] = W[n*128+k] * mask[k], cast fp16.
// ---------------------------------------------------------------------------
__global__ __launch_bounds__(256) void k_wt(const float* __restrict__ W,
                                            const float* __restrict__ mask,
                                            _Float16* __restrict__ Bt) {
    int o = blockIdx.x * 256 + threadIdx.x;
    if (o < DIM * DIM) Bt[o] = (_Float16)(W[o] * mask[o & 127]);
}

// ---------------------------------------------------------------------------
// Kernel 1: h = feat @ Bt^T via MFMA f32_16x16x32_f16, fp32 accumulate.
// Epilogue: sv[row] = exp(leaky_relu(h @ attn)) — softmax numerator per node
// (max-subtraction dropped: s bounded ±~3, exp(s)/sum(exp(s)) == reference).
// ---------------------------------------------------------------------------
__global__ __launch_bounds__(256) void k_gemm(const float* __restrict__ feat,
                                              const _Float16* __restrict__ Bt,
                                              const float* __restrict__ attn,
                                              _Float16* __restrict__ hh,
                                              float* __restrict__ s) {
    const int lane = threadIdx.x & 63;
    const int wv   = threadIdx.x >> 6;
    const int l15  = lane & 15;
    const int quad = lane >> 4;
    const int row0 = blockIdx.x * 64 + wv * 16;

    f32x4 acc[8];
#pragma unroll
    for (int nt = 0; nt < 8; ++nt) acc[nt] = (f32x4){0.f, 0.f, 0.f, 0.f};

    const int arow = row0 + l15;
    const bool okA = arow < NN;
    const float* ap = feat + (size_t)(okA ? arow : 0) * DIM + quad * 8;

#pragma unroll
    for (int kc = 0; kc < 4; ++kc) {
        half8 a;
        float4 f0 = ((const float4*)(ap + kc * 32))[0];
        float4 f1 = ((const float4*)(ap + kc * 32))[1];
        if (!okA) { f0 = make_float4(0, 0, 0, 0); f1 = make_float4(0, 0, 0, 0); }
        a[0] = (_Float16)f0.x; a[1] = (_Float16)f0.y;
        a[2] = (_Float16)f0.z; a[3] = (_Float16)f0.w;
        a[4] = (_Float16)f1.x; a[5] = (_Float16)f1.y;
        a[6] = (_Float16)f1.z; a[7] = (_Float16)f1.w;
#pragma unroll
        for (int nt = 0; nt < 8; ++nt) {
            half8 b = *(const half8*)(Bt + (size_t)(nt * 16 + l15) * DIM + kc * 32 + quad * 8);
            acc[nt] = __builtin_amdgcn_mfma_f32_16x16x32_f16(a, b, acc[nt], 0, 0, 0);
        }
    }

    float avv[8];
#pragma unroll
    for (int nt = 0; nt < 8; ++nt) avv[nt] = attn[nt * 16 + l15];

#pragma unroll
    for (int r = 0; r < 4; ++r) {
        int row = row0 + quad * 4 + r;
        float p = 0.f;
#pragma unroll
        for (int nt = 0; nt < 8; ++nt) p += acc[nt][r] * avv[nt];
        p += __shfl_xor(p, 1, 64);
        p += __shfl_xor(p, 2, 64);
        p += __shfl_xor(p, 4, 64);
        p += __shfl_xor(p, 8, 64);
        if (l15 == 0 && row < NN) {
            float lr = (p > 0.f) ? p : 0.01f * p;
            s[row] = __expf(lr);      // softmax numerator, per node
        }
    }

#pragma unroll
    for (int nt = 0; nt < 8; ++nt) {
#pragma unroll
        for (int r = 0; r < 4; ++r) {
            int row = row0 + quad * 4 + r;
            if (row < NN)
                hh[(size_t)row * DIM + nt * 16 + l15] = (_Float16)acc[nt][r];
        }
    }
}

// ---------------------------------------------------------------------------
// Kernel 2: per-block LDS histogram over coarse buckets. 1024 threads.
// ---------------------------------------------------------------------------
__global__ __launch_bounds__(1024) void k_bhist(const int* __restrict__ dst,
                                                int* __restrict__ gHist) {
    __shared__ int hist[NBK2];
    const int t = threadIdx.x, b = blockIdx.x;
    for (int i = t; i < NBK2; i += 1024) hist[i] = 0;
    __syncthreads();
    const int e0 = b * EPB;
    int e1 = e0 + EPB; if (e1 > EE) e1 = EE;
    for (int e = e0 + t; e < e1; e += 1024)
        atomicAdd(&hist[dst[e] >> 9], 1);
    __syncthreads();
    for (int i = t; i < NBK2; i += 1024)
        gHist[i * NCH + b] = hist[i];
}

// ---------------------------------------------------------------------------
// Kernels 3-4: exclusive scan of gHist (SCN = 49*1024 elements).
// boff (per-1024-chunk base) is applied by consumers: final offset of gHist
// element i is gHist[i] + boff[i>>10].
// ---------------------------------------------------------------------------
__global__ __launch_bounds__(256) void k_scan_a(const int* __restrict__ deg,
                                                int* __restrict__ excl,
                                                int* __restrict__ bsum) {
    __shared__ int wsum[4];
    __shared__ int woff[4];
    const int t = threadIdx.x, b = blockIdx.x;
    const int base = b * 1024 + t * 4;
    int v0 = deg[base + 0];
    int v1 = deg[base + 1];
    int v2 = deg[base + 2];
    int v3 = deg[base + 3];
    int tsum = v0 + v1 + v2 + v3;

    const int lane = t & 63, w = t >> 6;
    int incl = tsum;
#pragma unroll
    for (int d = 1; d < 64; d <<= 1) {
        int n = __shfl_up(incl, d, 64);
        if (lane >= d) incl += n;
    }
    if (lane == 63) wsum[w] = incl;
    __syncthreads();
    if (t == 0) {
        int run = 0;
#pragma unroll
        for (int i = 0; i < 4; ++i) { woff[i] = run; run += wsum[i]; }
        bsum[b] = run;
    }
    __syncthreads();
    int texcl = incl - tsum + woff[w];
    excl[base + 0] = texcl;
    excl[base + 1] = texcl + v0;
    excl[base + 2] = texcl + v0 + v1;
    excl[base + 3] = texcl + v0 + v1 + v2;
}

__global__ __launch_bounds__(64) void k_scan_b(const int* __restrict__ bsum,
                                               int* __restrict__ boff) {
    const int lane = threadIdx.x & 63;
    int v = (lane < NSB) ? bsum[lane] : 0;
    int incl = v;
#pragma unroll
    for (int d = 1; d < 64; d <<= 1) {
        int n = __shfl_up(incl, d, 64);
        if (lane >= d) incl += n;
    }
    if (lane < NSB) boff[lane] = incl - v;
}

// ---------------------------------------------------------------------------
// Kernel 5: partition scatter. Private contiguous region per (bucket,block)
// -> full-line writebacks, LDS-only atomics. boff folded in at cursor init.
// Payload: (src | dstLocal<<20, exp(s[src]) bits). 1024 threads.
// ---------------------------------------------------------------------------
__global__ __launch_bounds__(1024) void k_bscatter(const int* __restrict__ src,
                                                   const int* __restrict__ dst,
                                                   const float* __restrict__ s,
                                                   const int* __restrict__ gOff,
                                                   const int* __restrict__ boff,
                                                   int2* __restrict__ binned) {
    __shared__ int cur[NBK2];
    const int t = threadIdx.x, b = blockIdx.x;
    for (int i = t; i < NBK2; i += 1024) {
        int idx = i * NCH + b;
        cur[i] = gOff[idx] + boff[idx >> 10];
    }
    __syncthreads();
    const int e0 = b * EPB;
    int e1 = e0 + EPB; if (e1 > EE) e1 = EE;
    for (int e = e0 + t; e < e1; e += 1024) {
        int d  = dst[e];
        int si = src[e];
        float x = s[si];
        int bk   = d >> 9;
        int dloc = d & (BK - 1);
        int pos = atomicAdd(&cur[bk], 1);
        binned[pos] = make_int2(si | (dloc << 20), __float_as_int(x));
    }
}

// ---------------------------------------------------------------------------
// Kernel 6: per-bucket exact CSR placement + node CSR pointers. 1024 threads
// (16 waves/block — was 4; this kernel was the occupancy hole at 196 blocks).
// ---------------------------------------------------------------------------
__global__ __launch_bounds__(1024) void k_group(const int* __restrict__ gOff,
                                                const int* __restrict__ boff,
                                                const int2* __restrict__ binned,
                                                int2* __restrict__ pack,
                                                int* __restrict__ offs) {
    __shared__ int ldeg[BK];
    __shared__ int wpart[8];
    const int bk = blockIdx.x;
    const int t  = threadIdx.x;
    const int i0 = bk * NCH;
    const int base = gOff[i0] + boff[i0 >> 10];
    int endp;
    if (bk == NBK2 - 1) endp = EE;
    else {
        int i1 = (bk + 1) * NCH;
        endp = gOff[i1] + boff[i1 >> 10];
    }

    if (t < BK) ldeg[t] = 0;
    __syncthreads();
    for (int j = base + t; j < endp; j += 1024)
        atomicAdd(&ldeg[(binned[j].x >> 20) & (BK - 1)], 1);
    __syncthreads();

    // scan of 512 bins: first 512 threads (8 waves) + cross-wave combine
    int v = 0, incl = 0;
    const int lane = t & 63;
    if (t < BK) {
        v = ldeg[t];
        incl = v;
#pragma unroll
        for (int d = 1; d < 64; d <<= 1) {
            int n = __shfl_up(incl, d, 64);
            if (lane >= d) incl += n;
        }
        if (lane == 63) wpart[t >> 6] = incl;
    }
    __syncthreads();
    if (t == 0) {
        int run = 0;
#pragma unroll
        for (int i = 0; i < 8; ++i) { int tmp = wpart[i]; wpart[i] = run; run += tmp; }
    }
    __syncthreads();
    if (t < BK) {
        int excl = incl - v + wpart[t >> 6];
        int c = base + excl;
        int n = bk * BK + t;
        if (n < NN) offs[n] = c;
        ldeg[t] = c;                       // becomes the placement cursor
    }
    if (bk == NBK2 - 1 && t == 0) offs[NN] = EE;
    __syncthreads();

    for (int j = base + t; j < endp; j += 1024) {
        int2 e = binned[j];
        int dloc = (e.x >> 20) & (BK - 1);
        int si   = e.x & 0xFFFFF;
        int pos = atomicAdd(&ldeg[dloc], 1);
        pack[pos] = make_int2(si, e.y);
    }
}

// ---------------------------------------------------------------------------
// Kernel 7: one wave per dst node. Wave-uniform control via readfirstlane ->
// pack reads are scalar loads; unroll x8 keeps 8 row-gathers in flight;
// predicated tail (clamped index, zero weight).
// ---------------------------------------------------------------------------
__global__ __launch_bounds__(256) void k_agg(const _Float16* __restrict__ hh,
                                             const int* __restrict__ offs,
                                             const int2* __restrict__ pack,
                                             float* __restrict__ out) {
    const int lane = threadIdx.x & 63;
    const int wid  = __builtin_amdgcn_readfirstlane(blockIdx.x * 4 + (threadIdx.x >> 6));
    if (wid >= NN) return;
    const int beg = __builtin_amdgcn_readfirstlane(offs[wid]);
    const int end = __builtin_amdgcn_readfirstlane(offs[wid + 1]);

    const half2v* h2 = (const half2v*)hh;
    float l = 0.f;
    float2 acc[4];
#pragma unroll
    for (int j = 0; j < 4; ++j) acc[j] = make_float2(0.f, 0.f);

    int p = beg;
    for (; p + 8 <= end; p += 8) {
        int2 e[8];
#pragma unroll
        for (int j = 0; j < 8; ++j) e[j] = pack[p + j];
        half2v v[8];
#pragma unroll
        for (int j = 0; j < 8; ++j) v[j] = h2[((unsigned)e[j].x << 6) + lane];
#pragma unroll
        for (int j = 0; j < 8; ++j) {
            float w = __int_as_float(e[j].y);
            acc[j & 3].x = fmaf((float)v[j][0], w, acc[j & 3].x);
            acc[j & 3].y = fmaf((float)v[j][1], w, acc[j & 3].y);
            l += w;
        }
    }
    const int rem = end - p;            // 0..7
    if (rem > 0) {
        const int last = end - 1;
        int2 e[7];
#pragma unroll
        for (int j = 0; j < 7; ++j) {
            int q = p + j;
            e[j] = pack[q <= last ? q : last];
        }
        half2v v[7];
#pragma unroll
        for (int j = 0; j < 7; ++j) v[j] = h2[((unsigned)e[j].x << 6) + lane];
#pragma unroll
        for (int j = 0; j < 7; ++j) {
            float w = (j < rem) ? __int_as_float(e[j].y) : 0.f;
            acc[j & 3].x = fmaf((float)v[j][0], w, acc[j & 3].x);
            acc[j & 3].y = fmaf((float)v[j][1], w, acc[j & 3].y);
            l += w;
        }
    }

    float inv = (l > 0.f) ? (1.0f / l) : 0.f;
    float rx = fmaxf((acc[0].x + acc[1].x + acc[2].x + acc[3].x) * inv, 0.f);
    float ry = fmaxf((acc[0].y + acc[1].y + acc[2].y + acc[3].y) * inv, 0.f);
    ((float2*)out)[(size_t)wid * 64 + lane] = make_float2(rx, ry);
}

// ---------------------------------------------------------------------------
extern "C" void kernel_launch(void* const* d_in, const int* in_sizes, int n_in,
                              void* d_out, int out_size, void* d_ws, size_t ws_size,
                              hipStream_t stream) {
    const float* feat = (const float*)d_in[0];
    const float* mask = (const float*)d_in[1];
    const float* W    = (const float*)d_in[2];
    const float* attn = (const float*)d_in[3];
    const int*   src  = (const int*)d_in[4];
    const int*   dst  = (const int*)d_in[5];
    float* out = (float*)d_out;

    // Workspace carve-up (~52.5 MB total)
    char* ws = (char*)d_ws;
    size_t off = 0;
    auto alloc = [&](size_t bytes) -> void* {
        void* p = ws + off;
        off = (off + bytes + 511) & ~(size_t)511;
        return p;
    };
    _Float16* hh  = (_Float16*)alloc((size_t)NN * DIM * 2); // 25.6 MB
    float*  sv    = (float*)alloc((size_t)NN * 4);
    _Float16* Bt  = (_Float16*)alloc((size_t)DIM * DIM * 2);
    int*    gOff  = (int*)alloc((size_t)SCN * 4);           // 200 KB
    int*    offs  = (int*)alloc((size_t)(NN + 1) * 4);
    int*    bsum  = (int*)alloc((size_t)NSB * 4);
    int*    boff  = (int*)alloc((size_t)NSB * 4);
    int2*   binned= (int2*)alloc((size_t)EE * 8);           // 12.8 MB
    int2*   pack  = (int2*)alloc((size_t)EE * 8);           // 12.8 MB

    k_wt<<<(DIM * DIM + 255) / 256, 256, 0, stream>>>(W, mask, Bt);
    k_gemm<<<(NN + 63) / 64, 256, 0, stream>>>(feat, Bt, attn, hh, sv);
    k_bhist<<<NCH, 1024, 0, stream>>>(dst, gOff);
    k_scan_a<<<NSB, 256, 0, stream>>>(gOff, gOff, bsum);
    k_scan_b<<<1, 64, 0, stream>>>(bsum, boff);
    k_bscatter<<<NCH, 1024, 0, stream>>>(src, dst, sv, gOff, boff, binned);
    k_group<<<NBK2, 1024, 0, stream>>>(gOff, boff, binned, pack, offs);
    k_agg<<<(NN + 3) / 4, 256, 0, stream>>>(hh, offs, pack, out);
}